// Round 3
// baseline (329.077 us; speedup 1.0000x reference)
//
#include <hip/hip_runtime.h>
#include <hip/hip_bf16.h>
#include <stdint.h>

#define DEV __device__ __forceinline__

typedef __attribute__((ext_vector_type(8))) short short8;     // 8 bf16 (MFMA A/B frag, 32x32x16)
typedef __attribute__((ext_vector_type(16))) float f32x16;    // MFMA C/D frag (32x32)
typedef __attribute__((ext_vector_type(4))) float floatx4;

constexpr int NB = 131072;

// ---- packed bf16 weight layout (element offsets) ----
// A-frag packing for 32x32x16: idx = base + ((kc*NT + nt)*64 + lane)*8 + j
// value = W[k = 16kc + 8*(lane>>5) + j][n = 32nt + (lane&31)], bias row at k=K.
constexpr int OFF_W1 = 0;        // 13kc x 8nt x 512  (K=224: 199 state + td@199 + b1@200)
constexpr int OFF_W2 = 53248;    // 17 x 8 x 512      (K=256 + b2@256)
constexpr int OFF_W3 = 122880;   // 17 x 4 x 512      (K=256 + b3@256, N=128)
constexpr int OFF_WH = 157696;   // 9 x 8 x 512       (K=128 + bias@128; nt>>1 = head, h3=value)
constexpr int OFF_WA2= 194560;   // 5kc x 3h x 512    (K=64 + ba2@64, N=32)
constexpr int NWQ    = 202240;

// cq: plain f32 arrays; LN loads use float4 at 32t+8m+4hi (naturally aligned)
constexpr int C_G1=0, C_BE1=256, C_G2=512, C_BE2=768, C_G3=1024, C_BE3=1152,
  C_GH=1280, C_BEH=1536, C_WV2=1792, C_BV2=1856;
constexpr int NCONST=1860;

struct Ptrs {
  const float *state,*td,*W1,*b1,*g1,*be1,*W2,*b2,*g2,*be2,*W3,*b3,*g3,*be3,
    *Wv1,*bv1,*gv,*bev,*Wv2,*bv2,*Wa1,*ba1,*ga,*bea,*Wa2,*ba2;
  const int *et;
};

DEV unsigned short f2bf(float x){
  uint32_t u = __float_as_uint(x);
  u += 0x7fffu + ((u>>16)&1u);
  return (unsigned short)(u>>16);
}
DEV uint32_t pkbf(float a, float b){
  float2 f2; f2.x=a; f2.y=b;
  __hip_bfloat162 h = __float22bfloat162_rn(f2);
  union { __hip_bfloat162 h; uint32_t u; } cv; cv.h = h;
  return cv.u;
}

// =====================================================================
// prep: quantize + pack weights into 32x32x16 A-frag order, bias as extra k-row
// =====================================================================
__global__ void prep_kernel(Ptrs p, unsigned short* __restrict__ wq, float* __restrict__ cq){
  int idx = blockIdx.x*256 + threadIdx.x;
  if (idx < NWQ) {
    float v = 0.f;
    if (idx < OFF_W2) {                       // W1: K rows 0..198=state,199=td,200=b1
      int e=idx, kc=e>>12, li=e&4095, nt=li>>9, l=(li>>3)&63, j=li&7;
      int k = kc*16 + (l>>5)*8 + j, n = nt*32 + (l&31);
      if (k < 200) v = p.W1[k*256 + n];
      else if (k == 200) v = p.b1[n];
    } else if (idx < OFF_W3) {                // W2 + b2@256
      int e=idx-OFF_W2, kc=e>>12, li=e&4095, nt=li>>9, l=(li>>3)&63, j=li&7;
      int k = kc*16 + (l>>5)*8 + j, n = nt*32 + (l&31);
      if (k < 256) v = p.W2[k*256 + n];
      else if (k == 256) v = p.b2[n];
    } else if (idx < OFF_WH) {                // W3 + b3@256 (N=128)
      int e=idx-OFF_W3, kc=e>>11, li=e&2047, nt=li>>9, l=(li>>3)&63, j=li&7;
      int k = kc*16 + (l>>5)*8 + j, n = nt*32 + (l&31);
      if (k < 256) v = p.W3[k*128 + n];
      else if (k == 256) v = p.b3[n];
    } else if (idx < OFF_WA2) {               // Wa1/Wv1 + bias@128; head = nt>>1
      int e=idx-OFF_WH, kc=e>>12, li=e&4095, nt=li>>9, l=(li>>3)&63, j=li&7;
      int k = kc*16 + (l>>5)*8 + j;
      int h = nt>>1, nl = (nt&1)*32 + (l&31);
      if (k < 128) v = (h<3) ? p.Wa1[h*8192 + k*64 + nl] : p.Wv1[k*64 + nl];
      else if (k == 128) v = (h<3) ? p.ba1[h*64 + nl] : p.bv1[nl];
    } else {                                  // Wa2 + ba2@64
      int e=idx-OFF_WA2, kc=e/1536, li=e%1536, h=li>>9, l=(li>>3)&63, j=li&7;
      int k = kc*16 + (l>>5)*8 + j, nl = l&31;
      if (k < 64) v = p.Wa2[h*2048 + k*32 + nl];
      else if (k == 64) v = p.ba2[h*32 + nl];
    }
    wq[idx] = f2bf(v);
  } else if (idx < NWQ + NCONST) {
    int ci = idx - NWQ; float v = 0.f;
    if      (ci < 256)  v = p.g1[ci];
    else if (ci < 512)  v = p.be1[ci-256];
    else if (ci < 768)  v = p.g2[ci-512];
    else if (ci < 1024) v = p.be2[ci-768];
    else if (ci < 1152) v = p.g3[ci-1024];
    else if (ci < 1280) v = p.be3[ci-1152];
    else if (ci < 1536) { int i=ci-1280; v = (i<192)? p.ga[i]  : p.gv[i-192]; }
    else if (ci < 1792) { int i=ci-1536; v = (i<192)? p.bea[i] : p.bev[i-192]; }
    else if (ci < 1856) v = p.Wv2[ci-1792];
    else if (ci ==1856) v = p.bv2[0];
    cq[ci] = v;
  }
}

// =====================================================================
// device helpers
// =====================================================================
DEV floatx4 ld4(const float* p){ return *(const floatx4*)p; }

DEV short8 mk_frag(uint32_t w0, uint32_t w1, uint32_t w2, uint32_t w3){
  union { uint32_t u[4]; short8 s; } cv;
  cv.u[0]=w0; cv.u[1]=w1; cv.u[2]=w2; cv.u[3]=w3; return cv.s;
}
DEV void pl32swap(uint32_t &x, uint32_t &y){
  asm volatile("v_permlane32_swap_b32 %0, %1" : "+v"(x), "+v"(y));
}
DEV f32x16 mf(short8 a, short8 b, f32x16 c){
  return __builtin_amdgcn_mfma_f32_32x32x16_bf16(a, b, c, 0, 0, 0);
}

// transpose one 32-feature tile of C-layout f32 y[16] into two bf16 B-frags.
// target frag slice a: lane needs k=8hi+j -> words from regs 8a.. of both halves.
DEV void tile_to_frags(const float (&y)[16], short8 &f0, short8 &f1){
  uint32_t P0 = pkbf(y[0], y[1]), P1 = pkbf(y[2], y[3]);
  uint32_t Q0 = pkbf(y[4], y[5]), Q1 = pkbf(y[6], y[7]);
  pl32swap(P0, Q0); pl32swap(P1, Q1);
  f0 = mk_frag(P0, P1, Q0, Q1);
  uint32_t R0 = pkbf(y[8], y[9]),  R1 = pkbf(y[10], y[11]);
  uint32_t S0 = pkbf(y[12], y[13]),S1 = pkbf(y[14], y[15]);
  pl32swap(R0, S0); pl32swap(R1, S1);
  f1 = mk_frag(R0, R1, S0, S1);
}

// =====================================================================
// fused forward: wave owns 32 batch rows, all features. NO LDS, NO barriers.
// C layout (32x32x16): col = lane&31 (batch), row n = (r&3)+8*(r>>2)+4*(lane>>5)
// =====================================================================
__global__ __launch_bounds__(256,2) void dqn_main(
    const float* __restrict__ state, const float* __restrict__ td,
    const int* __restrict__ et, const unsigned short* __restrict__ wq,
    const float* __restrict__ cq, float* __restrict__ out)
{
  const int tid = threadIdx.x, wv = tid>>6, l = tid&63;
  const int hi = l>>5, c = l&31;
  const int b = blockIdx.x*128 + wv*32 + c;

  const float* sph = state + (size_t)b*199 + hi*8;   // lane row base (+hi half)
  const float  tdv = td[b];
  const int    etv = et[b];

  const f32x16 z16 = {0,0,0,0,0,0,0,0,0,0,0,0,0,0,0,0};
  const short8 bias_bf = mk_frag(hi==0 ? 0x3F80u : 0u, 0u, 0u, 0u);  // x=1 at k=K

  f32x16 acc[8];

  // ================= L1: x(224) -> h1(256) =================
  {
    #pragma unroll
    for (int t=0;t<8;t++) acc[t] = z16;
    const unsigned short* wl = wq + OFF_W1 + l*8;
    #pragma unroll
    for (int kc=0;kc<13;kc++){
      short8 bf;
      if (kc < 12){
        float v0=sph[kc*16+0], v1=sph[kc*16+1], v2=sph[kc*16+2], v3=sph[kc*16+3];
        float v4=sph[kc*16+4], v5=sph[kc*16+5], v6=sph[kc*16+6], v7=sph[kc*16+7];
        bf = mk_frag(pkbf(v0,v1), pkbf(v2,v3), pkbf(v4,v5), pkbf(v6,v7));
      } else {
        if (hi == 0){
          float v0=sph[192], v1=sph[193], v2=sph[194], v3=sph[195];
          float v4=sph[196], v5=sph[197], v6=sph[198], v7=tdv;
          bf = mk_frag(pkbf(v0,v1), pkbf(v2,v3), pkbf(v4,v5), pkbf(v6,v7));
        } else {
          bf = mk_frag(0x3F80u, 0u, 0u, 0u);   // k=200 -> 1.0 (b1 row), rest 0
        }
      }
      #pragma unroll
      for (int nt=0;nt<8;nt++)
        acc[nt] = mf(*(const short8*)(wl + (kc*8+nt)*512), bf, acc[nt]);
    }
  }

  // ---- handoff 1: LN(256) + relu -> B-frags ----
  short8 Bf[16];
  {
    float s=0.f, ss=0.f;
    #pragma unroll
    for (int t=0;t<8;t++)
      #pragma unroll
      for (int r=0;r<16;r++){ float v=acc[t][r]; s+=v; ss+=v*v; }
    s += __shfl_xor(s,32); ss += __shfl_xor(ss,32);
    float mu = s*(1.f/256.f);
    float rsv = rsqrtf(ss*(1.f/256.f) - mu*mu + 1e-5f);
    float mrs = mu*rsv;
    #pragma unroll
    for (int t=0;t<8;t++){
      float y[16];
      #pragma unroll
      for (int m=0;m<4;m++){
        floatx4 g4 = ld4(cq + C_G1  + t*32 + m*8 + hi*4);
        floatx4 e4 = ld4(cq + C_BE1 + t*32 + m*8 + hi*4);
        #pragma unroll
        for (int rr=0;rr<4;rr++){
          float tv = fmaf(acc[t][m*4+rr], rsv, -mrs);
          y[m*4+rr] = fmaxf(fmaf(tv, g4[rr], e4[rr]), 0.f);
        }
      }
      tile_to_frags(y, Bf[t*2], Bf[t*2+1]);
    }
  }

  // ================= L2: h1(256) -> h2(256) =================
  {
    #pragma unroll
    for (int t=0;t<8;t++) acc[t] = z16;
    const unsigned short* wl = wq + OFF_W2 + l*8;
    #pragma unroll
    for (int kc=0;kc<17;kc++){
      short8 bf = (kc<16) ? Bf[kc] : bias_bf;
      #pragma unroll
      for (int nt=0;nt<8;nt++)
        acc[nt] = mf(*(const short8*)(wl + (kc*8+nt)*512), bf, acc[nt]);
    }
  }

  // ---- handoff 2: LN(256) + relu -> B-frags ----
  {
    float s=0.f, ss=0.f;
    #pragma unroll
    for (int t=0;t<8;t++)
      #pragma unroll
      for (int r=0;r<16;r++){ float v=acc[t][r]; s+=v; ss+=v*v; }
    s += __shfl_xor(s,32); ss += __shfl_xor(ss,32);
    float mu = s*(1.f/256.f);
    float rsv = rsqrtf(ss*(1.f/256.f) - mu*mu + 1e-5f);
    float mrs = mu*rsv;
    #pragma unroll
    for (int t=0;t<8;t++){
      float y[16];
      #pragma unroll
      for (int m=0;m<4;m++){
        floatx4 g4 = ld4(cq + C_G2  + t*32 + m*8 + hi*4);
        floatx4 e4 = ld4(cq + C_BE2 + t*32 + m*8 + hi*4);
        #pragma unroll
        for (int rr=0;rr<4;rr++){
          float tv = fmaf(acc[t][m*4+rr], rsv, -mrs);
          y[m*4+rr] = fmaxf(fmaf(tv, g4[rr], e4[rr]), 0.f);
        }
      }
      tile_to_frags(y, Bf[t*2], Bf[t*2+1]);
    }
  }

  // ================= L3: h2(256) -> f(128) =================
  {
    #pragma unroll
    for (int t=0;t<4;t++) acc[t] = z16;
    const unsigned short* wl = wq + OFF_W3 + l*8;
    #pragma unroll
    for (int kc=0;kc<17;kc++){
      short8 bf = (kc<16) ? Bf[kc] : bias_bf;
      #pragma unroll
      for (int nt=0;nt<4;nt++)
        acc[nt] = mf(*(const short8*)(wl + (kc*4+nt)*512), bf, acc[nt]);
    }
  }

  // ---- handoff 3: LN(128) + relu -> f B-frags (8 slices) ----
  short8 Ff[8];
  {
    float s=0.f, ss=0.f;
    #pragma unroll
    for (int t=0;t<4;t++)
      #pragma unroll
      for (int r=0;r<16;r++){ float v=acc[t][r]; s+=v; ss+=v*v; }
    s += __shfl_xor(s,32); ss += __shfl_xor(ss,32);
    float mu = s*(1.f/128.f);
    float rsv = rsqrtf(ss*(1.f/128.f) - mu*mu + 1e-5f);
    float mrs = mu*rsv;
    #pragma unroll
    for (int t=0;t<4;t++){
      float y[16];
      #pragma unroll
      for (int m=0;m<4;m++){
        floatx4 g4 = ld4(cq + C_G3  + t*32 + m*8 + hi*4);
        floatx4 e4 = ld4(cq + C_BE3 + t*32 + m*8 + hi*4);
        #pragma unroll
        for (int rr=0;rr<4;rr++){
          float tv = fmaf(acc[t][m*4+rr], rsv, -mrs);
          y[m*4+rr] = fmaxf(fmaf(tv, g4[rr], e4[rr]), 0.f);
        }
      }
      tile_to_frags(y, Ff[t*2], Ff[t*2+1]);
    }
  }

  // ================= heads: f(128) -> 4x64 (h0..2 adv, h3 value) =================
  {
    #pragma unroll
    for (int t=0;t<8;t++) acc[t] = z16;
    const unsigned short* wl = wq + OFF_WH + l*8;
    #pragma unroll
    for (int kc=0;kc<9;kc++){
      short8 bf = (kc<8) ? Ff[kc] : bias_bf;
      #pragma unroll
      for (int nt=0;nt<8;nt++)
        acc[nt] = mf(*(const short8*)(wl + (kc*8+nt)*512), bf, acc[nt]);
    }
  }

  // ---- value head (tiles 6,7): LN(64)+relu, dot Wv2 ----
  float vval;
  {
    float s=0.f, ss=0.f;
    #pragma unroll
    for (int t=6;t<8;t++)
      #pragma unroll
      for (int r=0;r<16;r++){ float v=acc[t][r]; s+=v; ss+=v*v; }
    s += __shfl_xor(s,32); ss += __shfl_xor(ss,32);
    float mu = s*(1.f/64.f);
    float rsv = rsqrtf(ss*(1.f/64.f) - mu*mu + 1e-5f);
    float mrs = mu*rsv;
    float dot = 0.f;
    #pragma unroll
    for (int t=6;t<8;t++)
      #pragma unroll
      for (int m=0;m<4;m++){
        floatx4 g4 = ld4(cq + C_GH  + t*32 + m*8 + hi*4);
        floatx4 e4 = ld4(cq + C_BEH + t*32 + m*8 + hi*4);
        floatx4 w4 = ld4(cq + C_WV2 + (t-6)*32 + m*8 + hi*4);
        #pragma unroll
        for (int rr=0;rr<4;rr++){
          float tv = fmaf(acc[t][m*4+rr], rsv, -mrs);
          float y  = fmaxf(fmaf(tv, g4[rr], e4[rr]), 0.f);
          dot = fmaf(y, w4[rr], dot);
        }
      }
    dot += __shfl_xor(dot,32);
    vval = dot + cq[C_BV2];
  }

  // ---- adv heads h=0..2: LN(64)+relu -> a2 GEMM -> dueling combine ----
  const unsigned short* wla = wq + OFF_WA2 + l*8;
  #pragma unroll
  for (int h=0;h<3;h++){
    float s=0.f, ss=0.f;
    #pragma unroll
    for (int t2=0;t2<2;t2++){
      int t = 2*h + t2;
      #pragma unroll
      for (int r=0;r<16;r++){ float v=acc[t][r]; s+=v; ss+=v*v; }
    }
    s += __shfl_xor(s,32); ss += __shfl_xor(ss,32);
    float mu = s*(1.f/64.f);
    float rsv = rsqrtf(ss*(1.f/64.f) - mu*mu + 1e-5f);
    float mrs = mu*rsv;
    short8 Hf[4];
    #pragma unroll
    for (int t2=0;t2<2;t2++){
      int t = 2*h + t2;
      float y[16];
      #pragma unroll
      for (int m=0;m<4;m++){
        floatx4 g4 = ld4(cq + C_GH  + t*32 + m*8 + hi*4);
        floatx4 e4 = ld4(cq + C_BEH + t*32 + m*8 + hi*4);
        #pragma unroll
        for (int rr=0;rr<4;rr++){
          float tv = fmaf(acc[t][m*4+rr], rsv, -mrs);
          y[m*4+rr] = fmaxf(fmaf(tv, g4[rr], e4[rr]), 0.f);
        }
      }
      tile_to_frags(y, Hf[t2*2], Hf[t2*2+1]);
    }
    f32x16 a2 = z16;
    #pragma unroll
    for (int kc=0;kc<5;kc++){
      short8 bf = (kc<4) ? Hf[kc] : bias_bf;
      a2 = mf(*(const short8*)(wla + (kc*3+h)*512), bf, a2);
    }
    float sm = 0.f;
    #pragma unroll
    for (int r=0;r<16;r++) sm += a2[r];
    sm += __shfl_xor(sm,32);
    if (etv == h){
      float vm = vval - sm*(1.f/32.f);
      #pragma unroll
      for (int m=0;m<4;m++){
        floatx4 o;
        #pragma unroll
        for (int rr=0;rr<4;rr++) o[rr] = a2[m*4+rr] + vm;
        *(floatx4*)(out + (size_t)b*32 + m*8 + hi*4) = o;
      }
    }
  }
}

// =====================================================================
extern "C" void kernel_launch(void* const* d_in, const int* in_sizes, int n_in,
                              void* d_out, int out_size, void* d_ws, size_t ws_size,
                              hipStream_t stream)
{
  Ptrs p;
  p.state=(const float*)d_in[0];  p.td =(const float*)d_in[1];
  p.W1 =(const float*)d_in[2];  p.b1 =(const float*)d_in[3];  p.g1 =(const float*)d_in[4];  p.be1=(const float*)d_in[5];
  p.W2 =(const float*)d_in[6];  p.b2 =(const float*)d_in[7];  p.g2 =(const float*)d_in[8];  p.be2=(const float*)d_in[9];
  p.W3 =(const float*)d_in[10]; p.b3 =(const float*)d_in[11]; p.g3 =(const float*)d_in[12]; p.be3=(const float*)d_in[13];
  p.Wv1=(const float*)d_in[14]; p.bv1=(const float*)d_in[15]; p.gv =(const float*)d_in[16]; p.bev=(const float*)d_in[17];
  p.Wv2=(const float*)d_in[18]; p.bv2=(const float*)d_in[19];
  p.Wa1=(const float*)d_in[20]; p.ba1=(const float*)d_in[21]; p.ga =(const float*)d_in[22]; p.bea=(const float*)d_in[23];
  p.Wa2=(const float*)d_in[24]; p.ba2=(const float*)d_in[25];
  p.et =(const int*)d_in[26];

  unsigned short* wq = (unsigned short*)d_ws;
  float* cq = (float*)((char*)d_ws + (size_t)NWQ*2);

  const int prepN = NWQ + NCONST;
  hipLaunchKernelGGL(prep_kernel, dim3((prepN+255)/256), dim3(256), 0, stream, p, wq, cq);
  hipLaunchKernelGGL(dqn_main, dim3(NB/128), dim3(256), 0, stream,
                     p.state, p.td, p.et, (const unsigned short*)wq, (const float*)cq, (float*)d_out);
}

// Round 5
// 291.453 us; speedup vs baseline: 1.1291x; 1.1291x over previous
//
#include <hip/hip_runtime.h>
#include <hip/hip_bf16.h>
#include <stdint.h>

#define DEV __device__ __forceinline__

typedef __attribute__((ext_vector_type(8))) short short8;    // 8 bf16 (MFMA A/B frag)
typedef __attribute__((ext_vector_type(4))) float floatx4;   // MFMA C/D frag

constexpr int TM  = 64;     // rows per tile
constexpr int NB  = 131072; // batch
constexpr int AST = 264;    // act row stride (bf16 elems)

struct F4 { float x,y,z,w; };   // 4-byte-aligned float4 (x rows are odd-strided)

// ---- packed bf16 weight layout in d_ws (element offsets) ----
// A=weights, B=activations. Wave w owns a 64-col (L1/L2), 32-col (L3) n-slice.
constexpr int OFF_W1 = 0;        // 4w x 7kc x 4nt x 512   (K=224: 199 state + td@199 + BIAS@200)
constexpr int OFF_W2 = 57344;    // 4w x 8 x 4 x 512       (K=256, N=256)
constexpr int OFF_W3 = 122880;   // 4w x 8 x 2 x 512       (K=256, N=128)
constexpr int OFF_WH = 155648;   // 4h x 4 x 4 x 512       (K=128, N=64; h=0..2 adv, h=3 value)
constexpr int OFF_WA2= 188416;   // 3h x 2 x 2 x 512       (K=64,  N=32)
constexpr int NWQ    = 194560;

// cq layout: all float4-loadable bases 16B-aligned
constexpr int C_B1=0, C_G1=256, C_BE1=512, C_B2=768, C_G2=1024, C_BE2=1280,
  C_B3=1536, C_G3=1664, C_BE3=1792, C_BV1=1920, C_GV=1984, C_BEV=2048,
  C_WV2=2112, C_BV2=2176, C_BA1=2180, C_GA=2372, C_BEA=2564, C_BA2=2756;
constexpr int NCONST=2852;

struct Ptrs {
  const float *state,*td,*W1,*b1,*g1,*be1,*W2,*b2,*g2,*be2,*W3,*b3,*g3,*be3,
    *Wv1,*bv1,*gv,*bev,*Wv2,*bv2,*Wa1,*ba1,*ga,*bea,*Wa2,*ba2;
  const int *et;
};

DEV unsigned short f2bf(float x){
  uint32_t u = __float_as_uint(x);
  u += 0x7fffu + ((u>>16)&1u);
  return (unsigned short)(u>>16);
}
DEV uint32_t pkbf(float a, float b){
  float2 f2; f2.x=a; f2.y=b;
  __hip_bfloat162 h = __float22bfloat162_rn(f2);
  union { __hip_bfloat162 h; uint32_t u; } cv; cv.h = h;
  return cv.u;
}

// =====================================================================
// prep: quantize + transpose + pack weights (W1 carries b1 at k==200)
// (identical to the verified round-1 packing; cq table restored to R1 exactly)
// =====================================================================
__global__ void prep_kernel(Ptrs p, unsigned short* __restrict__ wq, float* __restrict__ cq){
  int idx = blockIdx.x*256 + threadIdx.x;
  if (idx < NWQ) {
    float v = 0.f;
    if (idx < OFF_W2) {                       // W1 (+bias row at k=200)
      int e = idx, w = e/14336, r = e%14336;
      int kc = r>>11, ct=(r>>9)&3, l=(r>>3)&63, j=r&7;
      int n = w*64 + ct*16 + (l&15);
      int k = kc*32 + (l>>4)*8 + j;
      if (k < 200) v = p.W1[k*256 + n];
      else if (k == 200) v = p.b1[n];
    } else if (idx < OFF_W3) {                // W2
      int e = idx-OFF_W2, w=e>>14, r=e&16383;
      int kc=r>>11, ct=(r>>9)&3, l=(r>>3)&63, j=r&7;
      int n = w*64 + ct*16 + (l&15);
      int k = kc*32 + (l>>4)*8 + j;
      v = p.W2[k*256 + n];
    } else if (idx < OFF_WH) {                // W3
      int e = idx-OFF_W3, w=e>>13, r=e&8191;
      int kc=r>>10, ct=(r>>9)&1, l=(r>>3)&63, j=r&7;
      int n = w*32 + ct*16 + (l&15);
      int k = kc*32 + (l>>4)*8 + j;
      v = p.W3[k*128 + n];
    } else if (idx < OFF_WA2) {               // Wv1/Wa1
      int e = idx-OFF_WH, h=e>>13, r=e&8191;
      int kc=r>>11, ct=(r>>9)&3, l=(r>>3)&63, j=r&7;
      int n = ct*16 + (l&15);
      int k = kc*32 + (l>>4)*8 + j;
      v = (h<3) ? p.Wa1[h*8192 + k*64 + n] : p.Wv1[k*64 + n];
    } else {                                  // Wa2
      int e = idx-OFF_WA2, h=e>>11, r=e&2047;
      int kc=r>>10, ct=(r>>9)&1, l=(r>>3)&63, j=r&7;
      int n = ct*16 + (l&15);
      int k = kc*32 + (l>>4)*8 + j;
      v = p.Wa2[h*2048 + k*32 + n];
    }
    wq[idx] = f2bf(v);
  } else if (idx < NWQ + NCONST) {
    int ci = idx - NWQ;
    float v;
    if      (ci < 256)  v = p.b1[ci];
    else if (ci < 512)  v = p.g1[ci-256];
    else if (ci < 768)  v = p.be1[ci-512];
    else if (ci < 1024) v = p.b2[ci-768];
    else if (ci < 1280) v = p.g2[ci-1024];
    else if (ci < 1536) v = p.be2[ci-1280];
    else if (ci < 1664) v = p.b3[ci-1536];
    else if (ci < 1792) v = p.g3[ci-1664];
    else if (ci < 1920) v = p.be3[ci-1792];
    else if (ci < 1984) v = p.bv1[ci-1920];
    else if (ci < 2048) v = p.gv[ci-1984];
    else if (ci < 2112) v = p.bev[ci-2048];
    else if (ci < 2176) v = p.Wv2[ci-2112];
    else if (ci < 2180) v = (ci==2176) ? p.bv2[0] : 0.f;   // bv2 + pad
    else if (ci < 2372) v = p.ba1[ci-2180];
    else if (ci < 2564) v = p.ga[ci-2372];
    else if (ci < 2756) v = p.bea[ci-2564];
    else                v = p.ba2[ci-2756];
    cq[ci] = v;
  }
}

// =====================================================================
// device helpers. C layout: col = batch row (lane&15), row = n = q*4+reg.
// =====================================================================
template<int RT>
DEV void zeroAccT(floatx4 (&acc)[RT][4]){
  const floatx4 z = {0.f,0.f,0.f,0.f};
  #pragma unroll
  for (int rt=0;rt<RT;rt++)
    #pragma unroll
    for (int ct=0;ct<4;ct++) acc[rt][ct]=z;
}

// streaming-weight GEMM: weights from L2 (compiler pipelines in the unroll),
// activations (B) from LDS, each weight frag reused across 4 batch tiles.
template<int KC,int RT>
DEV void runGemmW(floatx4 (&acc)[RT][4], const unsigned short* __restrict__ wp,
                  const unsigned short* __restrict__ aB, int aOff, int lane){
  #pragma unroll
  for (int kc=0;kc<KC;kc++){
    short8 a[4];
    #pragma unroll
    for (int c=0;c<4;c++)
      a[c] = *(const short8*)(aB + c*16*AST + aOff + kc*32);
    #pragma unroll
    for (int rt=0;rt<RT;rt++){
      short8 bw = *(const short8*)(wp + (kc*RT+rt)*512 + lane*8);
      #pragma unroll
      for (int c=0;c<4;c++)
        acc[rt][c] = __builtin_amdgcn_mfma_f32_16x16x32_bf16(bw, a[c], acc[rt][c], 0,0,0);
    }
  }
}

// L1 GEMM with B-frags built directly from global x (no LDS staging).
// B-frag: lane(q,ln) holds x[row = ct*16+ln][k = 32kc + 8q + j].
DEV void gemmL1G(floatx4 (&acc)[4][4], const unsigned short* __restrict__ wp,
                 const float* __restrict__ xb, const float* __restrict__ tdp,
                 int lane){
  const int q=lane>>4, ln=lane&15;
  #pragma unroll
  for (int kc=0;kc<7;kc++){
    short8 bfr[4];
    #pragma unroll
    for (int ct=0;ct<4;ct++){
      const float* rp = xb + (size_t)(ct*16+ln)*199;
      uint32_t w0,w1,w2,w3;
      if (kc<6){
        F4 lo = *(const F4*)(rp + kc*32 + q*8);
        F4 hi = *(const F4*)(rp + kc*32 + q*8 + 4);
        w0=pkbf(lo.x,lo.y); w1=pkbf(lo.z,lo.w); w2=pkbf(hi.x,hi.y); w3=pkbf(hi.z,hi.w);
      } else if (q==0){                      // k=192..198 + td@199
        F4 lo = *(const F4*)(rp + 192);
        float v4=rp[196], v5=rp[197], v6=rp[198], v7=tdp[ct*16+ln];
        w0=pkbf(lo.x,lo.y); w1=pkbf(lo.z,lo.w); w2=pkbf(v4,v5); w3=pkbf(v6,v7);
      } else if (q==1){                      // k=200 -> 1.0 (b1 row), rest 0
        w0=0x3F80u; w1=0u; w2=0u; w3=0u;
      } else {
        w0=0u; w1=0u; w2=0u; w3=0u;
      }
      union { uint32_t u[4]; short8 s; } cv;
      cv.u[0]=w0; cv.u[1]=w1; cv.u[2]=w2; cv.u[3]=w3;
      bfr[ct]=cv.s;
    }
    #pragma unroll
    for (int rt=0;rt<4;rt++){
      short8 bw = *(const short8*)(wp + (kc*4+rt)*512 + lane*8);
      #pragma unroll
      for (int c=0;c<4;c++)
        acc[rt][c] = __builtin_amdgcn_mfma_f32_16x16x32_bf16(bw, bfr[c], acc[rt][c], 0,0,0);
    }
  }
}

// bias fold + per-batch-row (s,ss): in-register adds, 2 shfls, LDS atomics.
template<int RT,bool BIAS>
DEV void statsT(floatx4 (&acc)[RT][4], const float* __restrict__ cq, int bo,
                float* sbuf, float* ssbuf, int q, int ln){
  if constexpr (BIAS){
    #pragma unroll
    for (int rt=0;rt<RT;rt++){
      floatx4 b4 = *(const floatx4*)(cq + bo + rt*16 + q*4);
      #pragma unroll
      for (int ct=0;ct<4;ct++) acc[rt][ct] += b4;
    }
  }
  #pragma unroll
  for (int ct=0;ct<4;ct++){
    float s=0.f, ss=0.f;
    #pragma unroll
    for (int rt=0;rt<RT;rt++)
      #pragma unroll
      for (int r=0;r<4;r++){ float v=acc[rt][ct][r]; s+=v; ss+=v*v; }
    s += __shfl_xor(s,16); ss += __shfl_xor(ss,16);
    s += __shfl_xor(s,32); ss += __shfl_xor(ss,32);
    if (q==0){
      atomicAdd(&sbuf[ct*16+ln], s);
      atomicAdd(&ssbuf[ct*16+ln], ss);
    }
  }
}

// LN apply + relu + natural-order packed bf16 write into the given act buffer
template<int RT>
DEV void lnWriteT(const floatx4 (&acc)[RT][4], const float* __restrict__ cq, int go, int beo,
                  const float* sbuf, const float* ssbuf, float invN,
                  unsigned short* act_, int colBase, int q, int ln){
  float mu[4], rs[4];
  #pragma unroll
  for (int ct=0;ct<4;ct++){
    float sv = sbuf[ct*16+ln], ssv = ssbuf[ct*16+ln];
    mu[ct] = sv*invN;
    rs[ct] = rsqrtf(ssv*invN - mu[ct]*mu[ct] + 1e-5f);
  }
  #pragma unroll
  for (int rt=0;rt<RT;rt++){
    floatx4 g4  = *(const floatx4*)(cq + go  + rt*16 + q*4);
    floatx4 be4 = *(const floatx4*)(cq + beo + rt*16 + q*4);
    #pragma unroll
    for (int ct=0;ct<4;ct++){
      float y[4];
      #pragma unroll
      for (int r=0;r<4;r++)
        y[r] = fmaxf((acc[rt][ct][r]-mu[ct])*rs[ct]*g4[r]+be4[r], 0.f);
      uint2 pk; pk.x = pkbf(y[0],y[1]); pk.y = pkbf(y[2],y[3]);
      *(uint2*)(act_ + (ct*16+ln)*AST + colBase + rt*16 + q*4) = pk;
    }
  }
}

// heads: wave w = head w (0..2 adv, 3 value). f(128)->64 per head, LN in-wave.
// Leaves relu'd y in acc (adv waves); value wave writes vb[row].
DEV void headPhase(floatx4 (&acc)[4][4], const float* __restrict__ cq,
                   const unsigned short* __restrict__ wq,
                   const unsigned short* __restrict__ actb, float* vb,
                   int w, int lane, int q, int ln){
  zeroAccT<4>(acc);
  runGemmW<4,4>(acc, wq + OFF_WH + w*8192, actb + ln*AST + q*8, 0, lane);
  const int bo = (w<3)? C_BA1+w*64 : C_BV1;
  const int go = (w<3)? C_GA +w*64 : C_GV;
  const int beo= (w<3)? C_BEA+w*64 : C_BEV;
  #pragma unroll
  for (int rt=0;rt<4;rt++){
    floatx4 b4 = *(const floatx4*)(cq + bo + rt*16 + q*4);
    #pragma unroll
    for (int ct=0;ct<4;ct++) acc[rt][ct] += b4;
  }
  float mu[4], rs[4];
  #pragma unroll
  for (int ct=0;ct<4;ct++){
    float s=0.f, ss=0.f;
    #pragma unroll
    for (int rt=0;rt<4;rt++)
      #pragma unroll
      for (int r=0;r<4;r++){ float v=acc[rt][ct][r]; s+=v; ss+=v*v; }
    s += __shfl_xor(s,16); ss += __shfl_xor(ss,16);
    s += __shfl_xor(s,32); ss += __shfl_xor(ss,32);
    mu[ct]=s*(1.f/64.f);
    rs[ct]=rsqrtf(ss*(1.f/64.f)-mu[ct]*mu[ct]+1e-5f);
  }
  #pragma unroll
  for (int rt=0;rt<4;rt++){
    floatx4 g4  = *(const floatx4*)(cq + go  + rt*16 + q*4);
    floatx4 be4 = *(const floatx4*)(cq + beo + rt*16 + q*4);
    #pragma unroll
    for (int ct=0;ct<4;ct++)
      #pragma unroll
      for (int r=0;r<4;r++)
        acc[rt][ct][r] = fmaxf((acc[rt][ct][r]-mu[ct])*rs[ct]*g4[r]+be4[r], 0.f);
  }
  if (w==3){
    float bv2v = cq[C_BV2];
    floatx4 wv4[4];
    #pragma unroll
    for (int rt=0;rt<4;rt++) wv4[rt] = *(const floatx4*)(cq + C_WV2 + rt*16 + q*4);
    #pragma unroll
    for (int ct=0;ct<4;ct++){
      float dot=0.f;
      #pragma unroll
      for (int rt=0;rt<4;rt++)
        #pragma unroll
        for (int r=0;r<4;r++) dot += acc[rt][ct][r]*wv4[rt][r];
      dot += __shfl_xor(dot,16);
      dot += __shfl_xor(dot,32);
      if (q==0) vb[ct*16+ln] = dot + bv2v;
    }
  }
}

// adv epilogue (waves 0..2): ha -> act cols[64w..), a2 GEMM, dueling combine.
DEV void advPhase(const floatx4 (&acc)[4][4], const float* __restrict__ cq,
                  const unsigned short* __restrict__ wq,
                  unsigned short* actb, const float* vb, const int* etlT,
                  float* __restrict__ outT, int w, int lane, int q, int ln){
  #pragma unroll
  for (int rt=0;rt<4;rt++)
    #pragma unroll
    for (int ct=0;ct<4;ct++){
      uint2 pk;
      pk.x = pkbf(acc[rt][ct][0], acc[rt][ct][1]);
      pk.y = pkbf(acc[rt][ct][2], acc[rt][ct][3]);
      *(uint2*)(actb + (ct*16+ln)*AST + 64*w + rt*16 + q*4) = pk;
    }
  floatx4 acc2[2][4];
  zeroAccT<2>(acc2);
  runGemmW<2,2>(acc2, wq + OFF_WA2 + w*2048, actb + ln*AST + q*8, 64*w, lane);
  #pragma unroll
  for (int rt=0;rt<2;rt++){
    floatx4 b4 = *(const floatx4*)(cq + C_BA2 + w*32 + rt*16 + q*4);
    #pragma unroll
    for (int ct=0;ct<4;ct++) acc2[rt][ct] += b4;
  }
  #pragma unroll
  for (int ct=0;ct<4;ct++){
    float sm=0.f;
    #pragma unroll
    for (int rt=0;rt<2;rt++)
      #pragma unroll
      for (int r=0;r<4;r++) sm += acc2[rt][ct][r];
    sm += __shfl_xor(sm,16);
    sm += __shfl_xor(sm,32);
    int b = ct*16+ln;
    if (etlT[b]==w){
      float vm = vb[b] - sm*(1.f/32.f);
      #pragma unroll
      for (int rt=0;rt<2;rt++){
        floatx4 o = acc2[rt][ct];
        o[0]+=vm; o[1]+=vm; o[2]+=vm; o[3]+=vm;
        *(floatx4*)(outT + (size_t)b*32 + rt*16 + q*4) = o;
      }
    }
  }
}

// =====================================================================
// fused forward: dual-tile software pipeline across barriers.
// Each phase pairs one tile's GEMM (MFMA/mem) with the other's LN-write (VALU).
// =====================================================================
__global__ __launch_bounds__(256,2) void dqn_main(
    const float* __restrict__ state, const float* __restrict__ td,
    const int* __restrict__ et, const unsigned short* __restrict__ wq,
    const float* __restrict__ cq, float* __restrict__ out)
{
  __shared__ __align__(16) unsigned short actA[TM*AST];   // 33 KB (tile 0)
  __shared__ __align__(16) unsigned short actB[TM*AST];   // 33 KB (tile 1)
  __shared__ float sstat[2][3][2][64];                    // [tile][layer][s/ss][row] 3 KB
  __shared__ float vbuf[2][64];
  __shared__ int   etl[2][64];

  const int tid=threadIdx.x, w=tid>>6, lane=tid&63, q=lane>>4, ln=lane&15;
  const int rowBlk = blockIdx.x*128;
  const float* x0 = state + (size_t)rowBlk*199;
  const float* x1 = x0 + (size_t)64*199;

  // ---- zero stats (once; each (tile,layer) slot written exactly once) ----
  ((float*)sstat)[tid]     = 0.f;
  ((float*)sstat)[tid+256] = 0.f;
  ((float*)sstat)[tid+512] = 0.f;
  if (tid < 128) ((int*)etl)[tid] = et[rowBlk+tid];
  __syncthreads();                                        // B0

  floatx4 aT0[4][4], aT1[4][4];

  // ---- P0: L1(T0) from global x ----
  zeroAccT<4>(aT0);
  gemmL1G(aT0, wq + OFF_W1 + w*14336, x0, td + rowBlk, lane);
  statsT<4,false>(aT0, cq, 0, sstat[0][0][0], sstat[0][0][1], q, ln);
  __syncthreads();                                        // B1

  // ---- P1: lnW1(T0->A) | L1(T1) ----
  lnWriteT<4>(aT0, cq, C_G1+w*64, C_BE1+w*64, sstat[0][0][0], sstat[0][0][1], 1.f/256.f, actA, w*64, q, ln);
  zeroAccT<4>(aT1);
  gemmL1G(aT1, wq + OFF_W1 + w*14336, x1, td + rowBlk + 64, lane);
  statsT<4,false>(aT1, cq, 0, sstat[1][0][0], sstat[1][0][1], q, ln);
  __syncthreads();                                        // B2

  // ---- P2: lnW1(T1->B) | L2(T0,A) ----
  lnWriteT<4>(aT1, cq, C_G1+w*64, C_BE1+w*64, sstat[1][0][0], sstat[1][0][1], 1.f/256.f, actB, w*64, q, ln);
  zeroAccT<4>(aT0);
  runGemmW<8,4>(aT0, wq + OFF_W2 + w*16384, actA + ln*AST + q*8, 0, lane);
  statsT<4,true>(aT0, cq, C_B2+w*64, sstat[0][1][0], sstat[0][1][1], q, ln);
  __syncthreads();                                        // B3

  // ---- P3: lnW2(T0->A) | L2(T1,B) ----
  lnWriteT<4>(aT0, cq, C_G2+w*64, C_BE2+w*64, sstat[0][1][0], sstat[0][1][1], 1.f/256.f, actA, w*64, q, ln);
  zeroAccT<4>(aT1);
  runGemmW<8,4>(aT1, wq + OFF_W2 + w*16384, actB + ln*AST + q*8, 0, lane);
  statsT<4,true>(aT1, cq, C_B2+w*64, sstat[1][1][0], sstat[1][1][1], q, ln);
  __syncthreads();                                        // B4

  // ---- P4: lnW2(T1->B) | L3(T0,A) ----
  lnWriteT<4>(aT1, cq, C_G2+w*64, C_BE2+w*64, sstat[1][1][0], sstat[1][1][1], 1.f/256.f, actB, w*64, q, ln);
  floatx4 c3T0[2][4];
  zeroAccT<2>(c3T0);
  runGemmW<8,2>(c3T0, wq + OFF_W3 + w*8192, actA + ln*AST + q*8, 0, lane);
  statsT<2,true>(c3T0, cq, C_B3+w*32, sstat[0][2][0], sstat[0][2][1], q, ln);
  __syncthreads();                                        // B5

  // ---- P5: lnW3(T0->A) | L3(T1,B) ----
  lnWriteT<2>(c3T0, cq, C_G3+w*32, C_BE3+w*32, sstat[0][2][0], sstat[0][2][1], 1.f/128.f, actA, w*32, q, ln);
  floatx4 c3T1[2][4];
  zeroAccT<2>(c3T1);
  runGemmW<8,2>(c3T1, wq + OFF_W3 + w*8192, actB + ln*AST + q*8, 0, lane);
  statsT<2,true>(c3T1, cq, C_B3+w*32, sstat[1][2][0], sstat[1][2][1], q, ln);
  __syncthreads();                                        // B6

  // ---- P6: lnW3(T1->B) | heads(T0,A) ----
  lnWriteT<2>(c3T1, cq, C_G3+w*32, C_BE3+w*32, sstat[1][2][0], sstat[1][2][1], 1.f/128.f, actB, w*32, q, ln);
  headPhase(aT0, cq, wq, actA, vbuf[0], w, lane, q, ln);
  __syncthreads();                                        // B7

  // ---- P7: heads(T1,B) | adv(T0,A) ----
  headPhase(aT1, cq, wq, actB, vbuf[1], w, lane, q, ln);
  if (w<3) advPhase(aT0, cq, wq, actA, vbuf[0], etl[0], out + (size_t)rowBlk*32, w, lane, q, ln);
  __syncthreads();                                        // B8

  // ---- P8: adv(T1,B) ----
  if (w<3) advPhase(aT1, cq, wq, actB, vbuf[1], etl[1], out + (size_t)(rowBlk+64)*32, w, lane, q, ln);
}

// =====================================================================
extern "C" void kernel_launch(void* const* d_in, const int* in_sizes, int n_in,
                              void* d_out, int out_size, void* d_ws, size_t ws_size,
                              hipStream_t stream)
{
  Ptrs p;
  p.state=(const float*)d_in[0];  p.td =(const float*)d_in[1];
  p.W1 =(const float*)d_in[2];  p.b1 =(const float*)d_in[3];  p.g1 =(const float*)d_in[4];  p.be1=(const float*)d_in[5];
  p.W2 =(const float*)d_in[6];  p.b2 =(const float*)d_in[7];  p.g2 =(const float*)d_in[8];  p.be2=(const float*)d_in[9];
  p.W3 =(const float*)d_in[10]; p.b3 =(const float*)d_in[11]; p.g3 =(const float*)d_in[12]; p.be3=(const float*)d_in[13];
  p.Wv1=(const float*)d_in[14]; p.bv1=(const float*)d_in[15]; p.gv =(const float*)d_in[16]; p.bev=(const float*)d_in[17];
  p.Wv2=(const float*)d_in[18]; p.bv2=(const float*)d_in[19];
  p.Wa1=(const float*)d_in[20]; p.ba1=(const float*)d_in[21]; p.ga =(const float*)d_in[22]; p.bea=(const float*)d_in[23];
  p.Wa2=(const float*)d_in[24]; p.ba2=(const float*)d_in[25];
  p.et =(const int*)d_in[26];

  unsigned short* wq = (unsigned short*)d_ws;
  float* cq = (float*)((char*)d_ws + (size_t)NWQ*2);

  const int prepN = NWQ + NCONST;
  hipLaunchKernelGGL(prep_kernel, dim3((prepN+255)/256), dim3(256), 0, stream, p, wq, cq);
  hipLaunchKernelGGL(dqn_main, dim3(NB/128), dim3(256), 0, stream,
                     p.state, p.td, p.et, (const unsigned short*)wq, (const float*)cq, (float*)d_out);
}